// Round 7
// baseline (82.148 us; speedup 1.0000x reference)
//
#include <hip/hip_runtime.h>

#define NT 256

typedef float f2 __attribute__((ext_vector_type(2)));

// ---- async global->LDS 16B ----
__device__ __forceinline__ void gload16(const float* g, float* l) {
  __builtin_amdgcn_global_load_lds(
      (const __attribute__((address_space(1))) void*)g,
      (__attribute__((address_space(3))) void*)l, 16, 0, 0);
}

// ================= meta body =================
// nw[o,i] = mb2 + sum_j mw2[j]*relu(mw1[3j]*vin[i] + mw1[3j+1]*W[o,i] + mw1[3j+2]*vout[o] + mb1[j])
__device__ __forceinline__ void meta_body(
    int g,
    const float* __restrict__ w1, const float* __restrict__ w2, const float* __restrict__ w3,
    const float* __restrict__ a0, const float* __restrict__ a1, const float* __restrict__ a2,
    const float* __restrict__ a3,
    float* __restrict__ n1, float* __restrict__ n2, float* __restrict__ n3,
    const float* __restrict__ mw1, const float* __restrict__ mb1,
    const float* __restrict__ mw2, const float* __restrict__ mb2) {
  const int n1c = (2048 * 1024) / 8;
  const int n2c = (2048 * 2048) / 8;

  const float* W; const float* vin; const float* vout; float* nw;
  int sh, e;
  if (g < n1c)            { W = w1; vin = a0; vout = a1; nw = n1; sh = 10; e = g; }
  else if (g < n1c + n2c) { W = w2; vin = a1; vout = a2; nw = n2; sh = 11; e = g - n1c; }
  else                    { W = w3; vin = a2; vout = a3; nw = n3; sh = 11; e = g - n1c - n2c; }

  const int base = e << 3;
  const int o = base >> sh;
  const int i0 = base & ((1 << sh) - 1);

  f2 wv[4], vv[4];
  {
    float4 t0 = *reinterpret_cast<const float4*>(&W[base]);
    float4 t1 = *reinterpret_cast<const float4*>(&W[base + 4]);
    wv[0] = (f2){t0.x, t0.y}; wv[1] = (f2){t0.z, t0.w};
    wv[2] = (f2){t1.x, t1.y}; wv[3] = (f2){t1.z, t1.w};
    float4 u0 = *reinterpret_cast<const float4*>(&vin[i0]);
    float4 u1 = *reinterpret_cast<const float4*>(&vin[i0 + 4]);
    vv[0] = (f2){u0.x, u0.y}; vv[1] = (f2){u0.z, u0.w};
    vv[2] = (f2){u1.x, u1.y}; vv[3] = (f2){u1.z, u1.w};
  }
  const float vo = vout[o];
  const float c2 = mb2[0];

  float r[32];
  #pragma unroll
  for (int j = 0; j < 32; ++j)
    r[j] = fmaf(mw1[3 * j + 2], vo, mb1[j]);

  f2 acc[4];
  #pragma unroll
  for (int p = 0; p < 4; ++p) acc[p] = (f2){c2, c2};

  const f2 zero = (f2){0.f, 0.f};
  #pragma unroll
  for (int j = 0; j < 32; ++j) {
    const float aj = mw1[3 * j];
    const float bj = mw1[3 * j + 1];
    const float mj = mw2[j];
    const f2 a2v = (f2){aj, aj};
    const f2 b2v = (f2){bj, bj};
    const f2 m2v = (f2){mj, mj};
    const f2 r2v = (f2){r[j], r[j]};
    #pragma unroll
    for (int p = 0; p < 4; ++p) {
#if __has_builtin(__builtin_elementwise_fma) && __has_builtin(__builtin_elementwise_max)
      f2 q = __builtin_elementwise_fma(a2v, vv[p], r2v);
      f2 h = __builtin_elementwise_fma(b2v, wv[p], q);
      h = __builtin_elementwise_max(h, zero);
      acc[p] = __builtin_elementwise_fma(m2v, h, acc[p]);
#else
      f2 h;
      h.x = fmaxf(fmaf(bj, wv[p].x, fmaf(aj, vv[p].x, r[j])), 0.f);
      h.y = fmaxf(fmaf(bj, wv[p].y, fmaf(aj, vv[p].y, r[j])), 0.f);
      acc[p].x = fmaf(mj, h.x, acc[p].x);
      acc[p].y = fmaf(mj, h.y, acc[p].y);
#endif
    }
  }

  *reinterpret_cast<float4*>(&nw[base])     = make_float4(acc[0].x, acc[0].y, acc[1].x, acc[1].y);
  *reinterpret_cast<float4*>(&nw[base + 4]) = make_float4(acc[2].x, acc[2].y, acc[3].x, acc[3].y);
}

// ================= gemm body =================
// Block 32b x 512o, thread 8b x 8o. A is transposed aT[k][32] read via scalar
// (wave-uniform) loads; W staged global->LDS async, double-buffered 16k chunks.
// P[sl*32+b][o] = sum_{k in slice} aT[k][b] * W[o][k]
template<int KLB, int OTL>
__device__ __forceinline__ void gemm_body(
    int bid, const float* __restrict__ AT, const float* __restrict__ W,
    float* __restrict__ P, int K, int O, float* __restrict__ Wt) {
  const int tid = threadIdx.x;
  const int l = tid & 63;
  const int otile = bid & ((1 << OTL) - 1);
  const int sl = bid >> OTL;
  const int obase = otile << 9;
  const int kbeg = sl * KLB;
  const int b0 = __builtin_amdgcn_readfirstlane((tid >> 6) << 3);
  constexpr int NCH = KLB / 16;

  float acc[8][8];
  #pragma unroll
  for (int j = 0; j < 8; ++j)
    #pragma unroll
    for (int i = 0; i < 8; ++i) acc[j][i] = 0.f;

  // stage one 512x16 chunk: LDS linear dest, source k4-group pre-swizzled
  auto stage = [&](int buf, int kc) {
    float* base = Wt + buf * 8192;
    #pragma unroll
    for (int q = 0; q < 8; ++q) {
      const int s = (q << 8) + tid;      // f4 slot 0..2047
      const int r = s >> 2;              // row 0..511
      const int p = s & 3;               // stored slot
      const float* gp = W + (size_t)(obase + r) * K + kc + ((p ^ ((r >> 1) & 3)) << 2);
      gload16(gp, base + (q << 10) + ((tid >> 6) << 8));
    }
  };

  stage(0, kbeg);
  __builtin_amdgcn_s_setprio(1);
  #pragma unroll 1
  for (int c = 0; c < NCH; ++c) {
    const int buf = c & 1;
    if (c + 1 < NCH) {
      stage(buf ^ 1, kbeg + (c + 1) * 16);
      asm volatile("s_waitcnt vmcnt(8)" ::: "memory");
    } else {
      asm volatile("s_waitcnt vmcnt(0)" ::: "memory");
    }
    __builtin_amdgcn_s_barrier();
    __builtin_amdgcn_sched_barrier(0);

    const float* Wb = Wt + buf * 8192;
    const int kc = kbeg + c * 16;
    #pragma unroll
    for (int gq = 0; gq < 4; ++gq) {
      float4 wv[8];
      #pragma unroll
      for (int i = 0; i < 8; ++i) {
        const int r = l + (i << 6);
        wv[i] = *reinterpret_cast<const float4*>(
            &Wb[(r << 4) + ((gq ^ ((r >> 1) & 3)) << 2)]);
      }
      const float* ap = AT + (size_t)(kc + (gq << 2)) * 32 + b0;  // uniform
      float av[4][8];
      #pragma unroll
      for (int kk = 0; kk < 4; ++kk)
        #pragma unroll
        for (int j = 0; j < 8; ++j)
          av[kk][j] = ap[(kk << 5) + j];
      #pragma unroll
      for (int kk = 0; kk < 4; ++kk)
        #pragma unroll
        for (int j = 0; j < 8; ++j)
          #pragma unroll
          for (int i = 0; i < 8; ++i)
            acc[j][i] = fmaf(av[kk][j],
                             reinterpret_cast<const float*>(&wv[i])[kk],
                             acc[j][i]);
    }
    __builtin_amdgcn_s_barrier();
  }
  __builtin_amdgcn_s_setprio(0);

  #pragma unroll
  for (int j = 0; j < 8; ++j) {
    float* pr = P + (size_t)(sl * 32 + b0 + j) * O + obase + l;
    #pragma unroll
    for (int i = 0; i < 8; ++i)
      pr[i << 6] = acc[j][i];
  }
}

// ================= transpose x[32][1024] -> xT[1024][32] =================
__device__ __forceinline__ void transp_body(int lbid, int tid,
                                            const float* __restrict__ x,
                                            float* __restrict__ xT) {
  __shared__ float T[32][33];
  const int k0 = lbid * 32;
  {
    const int b = tid >> 3, k4 = tid & 7;
    const float4 v = *reinterpret_cast<const float4*>(&x[b * 1024 + k0 + (k4 << 2)]);
    T[(k4 << 2) + 0][b] = v.x; T[(k4 << 2) + 1][b] = v.y;
    T[(k4 << 2) + 2][b] = v.z; T[(k4 << 2) + 3][b] = v.w;
  }
  __syncthreads();
  {
    const int k = tid >> 3, bq = tid & 7;
    float4 w = make_float4(T[k][(bq << 2)], T[k][(bq << 2) + 1],
                           T[k][(bq << 2) + 2], T[k][(bq << 2) + 3]);
    *reinterpret_cast<float4*>(&xT[(k0 + k) * 32 + (bq << 2)]) = w;
  }
}

// ================= gemv: row-0 activation chain =================
__device__ __forceinline__ void gemv_body(
    int lbid, int tid,
    const float* __restrict__ vX, const float* __restrict__ vW,
    const float* __restrict__ vB, float* __restrict__ vR, int vK) {
  const int w = tid >> 6, l = tid & 63;
  const int obase = lbid * 16 + w * 4;
  const int nt = vK >> 8;                 // 4 or 8
  float4 xv[8];
  #pragma unroll 8
  for (int t = 0; t < nt; ++t)
    xv[t] = *reinterpret_cast<const float4*>(&vX[(l + (t << 6)) << 2]);
  #pragma unroll
  for (int q = 0; q < 4; ++q) {
    const int o = obase + q;
    const float* wr = vW + (size_t)o * vK;
    float a = 0.f;
    #pragma unroll 8
    for (int t = 0; t < nt; ++t) {
      const float4 wv = *reinterpret_cast<const float4*>(&wr[(l + (t << 6)) << 2]);
      a = fmaf(wv.x, xv[t].x, a); a = fmaf(wv.y, xv[t].y, a);
      a = fmaf(wv.z, xv[t].z, a); a = fmaf(wv.w, xv[t].w, a);
    }
    #pragma unroll
    for (int m = 32; m >= 1; m >>= 1)
      a += __shfl_xor(a, m, 64);
    if (l == 0) vR[o] = fmaxf(a + vB[o], 0.f);
  }
}

// ================= reduce: sum NS slices + bias + relu =================
// mode 0: write aT[o][b]; mode 1: write out[b][o] (b-major)
__device__ __forceinline__ void red_body(
    int lbid, int tid, const float* __restrict__ P, const float* __restrict__ bias,
    float* __restrict__ dst, int NS, int OL4, int mode) {
  const int idx = lbid * NT + tid;
  const int o4 = idx & ((1 << OL4) - 1);
  const int b = idx >> OL4;
  const int O = 4 << OL4;
  float4 s = make_float4(0.f, 0.f, 0.f, 0.f);
  #pragma unroll 8
  for (int sl = 0; sl < NS; ++sl) {
    const float4 v = *reinterpret_cast<const float4*>(&P[(size_t)(sl * 32 + b) * O + (o4 << 2)]);
    s.x += v.x; s.y += v.y; s.z += v.z; s.w += v.w;
  }
  const float4 bv = *reinterpret_cast<const float4*>(&bias[o4 << 2]);
  s.x = fmaxf(s.x + bv.x, 0.f); s.y = fmaxf(s.y + bv.y, 0.f);
  s.z = fmaxf(s.z + bv.z, 0.f); s.w = fmaxf(s.w + bv.w, 0.f);
  if (mode == 0) {
    const int o = o4 << 2;
    dst[(o + 0) * 32 + b] = s.x; dst[(o + 1) * 32 + b] = s.y;
    dst[(o + 2) * 32 + b] = s.z; dst[(o + 3) * 32 + b] = s.w;
  } else {
    *reinterpret_cast<float4*>(&dst[(size_t)b * O + (o4 << 2)]) = s;
  }
}

// ================= role-dispatch kernel =================
template<int HG, int KLB, int OTL>
__global__ __launch_bounds__(NT) void step(
    int nGemm, const float* GA, const float* GW, float* GP, int GK, int GO,
    int nTrans, const float* TX, float* TXT,
    int nGemv, const float* vX, const float* vW, const float* vB, float* vR, int vK,
    int nRed, const float* RP, const float* Rb, float* RD, int RNS, int ROL4, int RMODE,
    int mStart,
    const float* w1, const float* w2, const float* w3,
    const float* a0, const float* a1r, const float* a2r, const float* a3r,
    float* n1, float* n2, float* n3,
    const float* mw1, const float* mb1, const float* mw2, const float* mb2) {
  const int bid = blockIdx.x;
  const int tid = threadIdx.x;
  if constexpr (HG != 0) {
    if (bid < nGemm) {
      __shared__ float Wt[2 * 512 * 16];   // 64 KB
      gemm_body<KLB, OTL>(bid, GA, GW, GP, GK, GO, Wt);
      return;
    }
  }
  int b = bid - nGemm;
  if (b < nTrans) { transp_body(b, tid, TX, TXT); return; }
  b -= nTrans;
  if (b < nGemv) { gemv_body(b, tid, vX, vW, vB, vR, vK); return; }
  b -= nGemv;
  if (b < nRed) { red_body(b, tid, RP, Rb, RD, RNS, ROL4, RMODE); return; }
  b -= nRed;
  const int g = (mStart + b) * NT + tid;
  meta_body(g, w1, w2, w3, a0, a1r, a2r, a3r, n1, n2, n3, mw1, mb1, mw2, mb2);
}

extern "C" void kernel_launch(void* const* d_in, const int* in_sizes, int n_in,
                              void* d_out, int out_size, void* d_ws, size_t ws_size,
                              hipStream_t stream) {
  const float* x   = (const float*)d_in[0];
  const float* w1  = (const float*)d_in[1];
  const float* b1  = (const float*)d_in[2];
  const float* w2  = (const float*)d_in[3];
  const float* b2  = (const float*)d_in[4];
  const float* w3  = (const float*)d_in[5];
  const float* b3  = (const float*)d_in[6];
  const float* mw1 = (const float*)d_in[7];
  const float* mb1 = (const float*)d_in[8];
  const float* mw2 = (const float*)d_in[9];
  const float* mb2 = (const float*)d_in[10];

  float* out = (float*)d_out;                 // [32][1024]
  float* n1  = out + 32 * 1024;               // [2048][1024]
  float* n2  = n1 + 2048 * 1024;              // [2048][2048]
  float* n3  = n2 + 2048 * 2048;              // [1024][2048]

  float* ws     = (float*)d_ws;
  float* xT     = ws;                         // 1024*32
  float* a1T    = xT + 32768;                 // 2048*32
  float* a2T    = a1T + 65536;                // 2048*32
  float* a1row  = a2T + 65536;                // 2048
  float* a2row  = a1row + 2048;               // 2048
  float* outrow = a2row + 2048;               // 1024
  float* P1     = outrow + 1024;              // 32*32*2048 = 2M f
  float* P2     = P1 + 2097152;               // 2M f
  float* P3     = P2 + 2097152;               // 64*32*1024 = 2M f

  #define MARGS w1, w2, w3, x, a1row, a2row, outrow, n1, n2, n3, mw1, mb1, mw2, mb2
  #define NOGEMM 0, nullptr, nullptr, nullptr, 0, 0
  #define NOTRANS 0, nullptr, nullptr
  #define NOGEMV 0, nullptr, nullptr, nullptr, nullptr, 0
  #define NORED 0, nullptr, nullptr, nullptr, 0, 0, 0

  // K0: transpose x (32) + gemv1 x->a1row (128)
  step<0, 16, 0><<<160, NT, 0, stream>>>(
      NOGEMM, 32, x, xT, 128, x, w1, b1, a1row, 1024, NORED, 4096, MARGS);
  // K1: gemm1 xT@w1->P1 (128) + gemv2 a1row->a2row (128) + meta blk [0,1024)
  step<1, 32, 2><<<1280, NT, 0, stream>>>(
      128, xT, w1, P1, 1024, 2048, NOTRANS, 128, a1row, w2, b2, a2row, 2048,
      NORED, 0, MARGS);
  // K2: red1 P1->a1T (64) + gemv3 a2row->outrow (64) + meta blk [1024,2224)
  step<0, 16, 0><<<1328, NT, 0, stream>>>(
      NOGEMM, NOTRANS, 64, a2row, w3, b3, outrow, 2048,
      64, P1, b1, a1T, 32, 9, 0, 1024, MARGS);
  // K3: gemm2 a1T@w2->P2 (128) + meta blk [2224,3328)
  step<1, 64, 2><<<1232, NT, 0, stream>>>(
      128, a1T, w2, P2, 2048, 2048, NOTRANS, NOGEMV, NORED, 2224, MARGS);
  // K4: red2 P2->a2T (64) + meta blk [3328,3840)
  step<0, 16, 0><<<576, NT, 0, stream>>>(
      NOGEMM, NOTRANS, NOGEMV, 64, P2, b2, a2T, 32, 9, 0, 3328, MARGS);
  // K5: gemm3 a2T@w3->P3 (128) + meta blk [3840,4096)
  step<1, 32, 1><<<384, NT, 0, stream>>>(
      128, a2T, w3, P3, 2048, 1024, NOTRANS, NOGEMV, NORED, 3840, MARGS);
  // K6: red3 P3->out b-major (32)
  step<0, 16, 0><<<32, NT, 0, stream>>>(
      NOGEMM, NOTRANS, NOGEMV, 32, P3, b3, out, 64, 8, 1, 4096, MARGS);

  #undef MARGS
  #undef NOGEMM
  #undef NOTRANS
  #undef NOGEMV
  #undef NORED
}